// Round 1
// baseline (1942.928 us; speedup 1.0000x reference)
//
#include <hip/hip_runtime.h>

#define DIM 256
#define NEMB 8192
#define NQ 32768
#define OUT_Q_ELEMS 8388608   // 8*4096*256

// ---------------------------------------------------------------------------
// Kernel 1: codebook squared norms in double (precision anchor for argmin)
// embed is [DIM][NEMB] row-major; column j norm. Coalesced across j.
// ---------------------------------------------------------------------------
__global__ void enorm_kernel(const float* __restrict__ embed,
                             double* __restrict__ enorm) {
    int j = blockIdx.x * blockDim.x + threadIdx.x;
    if (j < NEMB) {
        double s = 0.0;
        for (int d = 0; d < DIM; ++d) {
            double v = (double)embed[(size_t)d * NEMB + j];
            s += v * v;
        }
        enorm[j] = s;
    }
}

// ---------------------------------------------------------------------------
// Kernel 2: argmin over codes. Register-tiled fp32 GEMM (8x8 micro-tile),
// fp64 distance compare: dist = ||e||^2 - 2*x.e  (||x||^2 dropped: row-const).
// Block: 256 threads, M=64 queries; N-loop tiles of 256 codes; K chunks of 32.
// ---------------------------------------------------------------------------
__global__ __launch_bounds__(256, 2) void argmin_kernel(
    const float* __restrict__ input, const float* __restrict__ embed,
    const double* __restrict__ enorm, int* __restrict__ widx,
    float* __restrict__ out_idx) {
    __shared__ float Xs[32][64];    // [k][m]  8 KB
    __shared__ float Es[32][256];   // [k][n] 32 KB
    __shared__ double redv[64][32]; // 16 KB
    __shared__ int    redi[64][32]; //  8 KB

    const int tid = threadIdx.x;
    const int tm  = tid >> 5;   // 0..7   (8 query rows each)
    const int tn  = tid & 31;   // 0..31  (8 codes each, strided)
    const int w   = tid >> 6;   // wave id 0..3
    const int l   = tid & 63;   // lane 0..63
    const int qb  = blockIdx.x * 64;

    double bestv[8];
    int    bestc[8];
#pragma unroll
    for (int i = 0; i < 8; ++i) { bestv[i] = 1e300; bestc[i] = 0; }

    for (int nt = 0; nt < NEMB / 256; ++nt) {
        const int nb = nt * 256;
        float acc[8][8];
#pragma unroll
        for (int i = 0; i < 8; ++i)
#pragma unroll
            for (int j = 0; j < 8; ++j) acc[i][j] = 0.0f;

        for (int kc = 0; kc < DIM / 32; ++kc) {
            const int k0 = kc * 32;
            __syncthreads();
            // ---- stage X chunk, transposed to [k][m]. lane l = query row,
            //      wave w covers k columns 8w..8w+7. LDS writes hit bank l%32
            //      (2-way aliasing = free).
            {
                const float* xp = input + (size_t)(qb + l) * DIM + k0 + 8 * w;
                float4 a0 = *(const float4*)xp;
                float4 a1 = *(const float4*)(xp + 4);
                Xs[8 * w + 0][l] = a0.x; Xs[8 * w + 1][l] = a0.y;
                Xs[8 * w + 2][l] = a0.z; Xs[8 * w + 3][l] = a0.w;
                Xs[8 * w + 4][l] = a1.x; Xs[8 * w + 5][l] = a1.y;
                Xs[8 * w + 6][l] = a1.z; Xs[8 * w + 7][l] = a1.w;
            }
            // ---- stage E chunk [k][n]: each 64-lane group copies one k-row
            //      of 256 contiguous floats (fully coalesced, contiguous LDS).
#pragma unroll
            for (int i = 0; i < 8; ++i) {
                const int k = 4 * i + w;
                const int n = 4 * l;
                *(float4*)&Es[k][n] =
                    *(const float4*)(embed + (size_t)(k0 + k) * NEMB + nb + n);
            }
            __syncthreads();
            // ---- inner product: 64 FMA per k per thread
#pragma unroll 8
            for (int k = 0; k < 32; ++k) {
                float xv[8], ev[8];
                *(float4*)&xv[0] = *(const float4*)&Xs[k][8 * tm];
                *(float4*)&xv[4] = *(const float4*)&Xs[k][8 * tm + 4];
                *(float2*)&ev[0] = *(const float2*)&Es[k][2 * tn];        // p=0
                *(float2*)&ev[2] = *(const float2*)&Es[k][64 + 2 * tn];   // p=1
                *(float2*)&ev[4] = *(const float2*)&Es[k][128 + 2 * tn];  // p=2
                *(float2*)&ev[6] = *(const float2*)&Es[k][192 + 2 * tn];  // p=3
#pragma unroll
                for (int i = 0; i < 8; ++i)
#pragma unroll
                    for (int j = 0; j < 8; ++j)
                        acc[i][j] = fmaf(xv[i], ev[j], acc[i][j]);
            }
        }
        // ---- epilogue: fp64 distance, running argmin (ascending c order)
#pragma unroll
        for (int p = 0; p < 4; ++p) {
#pragma unroll
            for (int s = 0; s < 2; ++s) {
                const int c = nb + 64 * p + 2 * tn + s;
                const double en = enorm[c];
#pragma unroll
                for (int i = 0; i < 8; ++i) {
                    double dist = en - 2.0 * (double)acc[i][2 * p + s];
                    if (dist < bestv[i]) { bestv[i] = dist; bestc[i] = c; }
                }
            }
        }
    }
    // ---- cross-thread (over tn) argmin reduction per query row
#pragma unroll
    for (int i = 0; i < 8; ++i) {
        redv[8 * tm + i][tn] = bestv[i];
        redi[8 * tm + i][tn] = bestc[i];
    }
    __syncthreads();
    if (tid < 64) {
        double bv = redv[tid][0];
        int    bc = redi[tid][0];
        for (int t = 1; t < 32; ++t) {
            double v = redv[tid][t];
            int    c = redi[tid][t];
            if (v < bv || (v == bv && c < bc)) { bv = v; bc = c; }
        }
        widx[qb + tid]    = bc;
        out_idx[qb + tid] = (float)bc;
    }
}

// ---------------------------------------------------------------------------
// Kernel 3: gather winning code rows + per-query squared-diff partial (fp64).
// One block per query; thread t = dim element.
// ---------------------------------------------------------------------------
__global__ void gather_kernel(const float* __restrict__ input,
                              const float* __restrict__ embed,
                              const int* __restrict__ widx,
                              float* __restrict__ out_q,
                              double* __restrict__ partials) {
    const int q = blockIdx.x;
    const int t = threadIdx.x;  // 0..255 == DIM
    const int j = widx[q];
    const float e = embed[(size_t)t * NEMB + j];  // column gather (L2-resident)
    const float x = input[(size_t)q * DIM + t];
    out_q[(size_t)q * DIM + t] = e;
    const float d = e - x;
    double v = (double)d * (double)d;
#pragma unroll
    for (int off = 32; off >= 1; off >>= 1) v += __shfl_down(v, off, 64);
    __shared__ double red[4];
    if ((t & 63) == 0) red[t >> 6] = v;
    __syncthreads();
    if (t == 0) partials[q] = red[0] + red[1] + red[2] + red[3];
}

// ---------------------------------------------------------------------------
// Kernel 4: reduce 32768 partials -> mean -> d_out diff slot
// ---------------------------------------------------------------------------
__global__ void diff_kernel(const double* __restrict__ partials,
                            float* __restrict__ out_diff) {
    const int t = threadIdx.x;  // 256
    double s = 0.0;
    for (int i = t; i < NQ; i += 256) s += partials[i];
#pragma unroll
    for (int off = 32; off >= 1; off >>= 1) s += __shfl_down(s, off, 64);
    __shared__ double red[4];
    if ((t & 63) == 0) red[t >> 6] = s;
    __syncthreads();
    if (t == 0)
        out_diff[0] = (float)((red[0] + red[1] + red[2] + red[3]) /
                              (double)OUT_Q_ELEMS);
}

extern "C" void kernel_launch(void* const* d_in, const int* in_sizes, int n_in,
                              void* d_out, int out_size, void* d_ws,
                              size_t ws_size, hipStream_t stream) {
    const float* input = (const float*)d_in[0];  // [8,4096,256] fp32
    const float* embed = (const float*)d_in[1];  // [256,8192]  fp32

    // outputs concatenated: quantize [8388608] | diff [1] | embed_ind [32768]
    float* out_q    = (float*)d_out;
    float* out_diff = out_q + OUT_Q_ELEMS;
    float* out_idx  = out_diff + 1;

    // workspace: enorm64 (64 KB) | widx (128 KB) | partials (256 KB)
    double* enorm    = (double*)d_ws;
    int*    widx     = (int*)((char*)d_ws + 65536);
    double* partials = (double*)((char*)d_ws + 65536 + 131072);

    hipLaunchKernelGGL(enorm_kernel, dim3(NEMB / 256), dim3(256), 0, stream,
                       embed, enorm);
    hipLaunchKernelGGL(argmin_kernel, dim3(NQ / 64), dim3(256), 0, stream,
                       input, embed, enorm, widx, out_idx);
    hipLaunchKernelGGL(gather_kernel, dim3(NQ), dim3(256), 0, stream,
                       input, embed, widx, out_q, partials);
    hipLaunchKernelGGL(diff_kernel, dim3(1), dim3(256), 0, stream,
                       partials, out_diff);
}